// Round 3
// baseline (82.514 us; speedup 1.0000x reference)
//
#include <hip/hip_runtime.h>
#include <hip/hip_bf16.h>
#include <math.h>

#define N_PAIR 8192
#define DIM 128
#define L2REG 0.05f
#define LOG2E 1.44269504088896340736f
#define LN2 0.69314718055994530942f
#define SHIFT 64.0f

#define CS 32                           // column splits
#define ROWS_PER_BLOCK 128              // 4 waves x 32 rows
#define COLS_PER_BLOCK (N_PAIR / CS)    // 256
#define CT (COLS_PER_BLOCK / 16)        // 16 col tiles

typedef __attribute__((ext_vector_type(8))) short short8;
typedef __attribute__((ext_vector_type(4))) float f32x4;

static __device__ __forceinline__ float fast_exp2(float x) {
#if __has_builtin(__builtin_amdgcn_exp2f)
  return __builtin_amdgcn_exp2f(x);
#else
  float r;
  asm("v_exp_f32 %0, %1" : "=v"(r) : "v"(x));
  return r;
#endif
}

// ---------------- prep: deinterleave, scale anc by log2e, cast bf16, norms + diag ----
// one wave per pair (pair = 256 contiguous floats); 4 pairs per block.
// lanes 0-31: anc (row 2i), lanes 32-63: pos (row 2i+1); 1 float4 per lane.
__global__ __launch_bounds__(256) void prep_kernel(
    const float* __restrict__ img,
    ushort* __restrict__ anc_bf, ushort* __restrict__ pos_bf,
    float* __restrict__ diag, float* __restrict__ na, float* __restrict__ npn) {
  int pair = blockIdx.x * 4 + (threadIdx.x >> 6);
  int lane = threadIdx.x & 63;
  const float4* base = (const float4*)(img + (size_t)pair * 2 * DIM);
  float4 v = base[lane];
  // partner half's values (anc lanes receive pos, and vice versa)
  float4 o;
  o.x = __shfl_xor(v.x, 32);
  o.y = __shfl_xor(v.y, 32);
  o.z = __shfl_xor(v.z, 32);
  o.w = __shfl_xor(v.w, 32);

  float ss = v.x * v.x + v.y * v.y + v.z * v.z + v.w * v.w;
  float sd = v.x * o.x + v.y * o.y + v.z * o.z + v.w * o.w;
  #pragma unroll
  for (int off = 1; off < 32; off <<= 1) {   // reduce within each 32-half
    ss += __shfl_xor(ss, off);
    sd += __shfl_xor(sd, off);
  }
  float ss_other = __shfl_xor(ss, 32);       // lane0 gets pos norm^2
  if (lane == 0) {
    diag[pair] = sd;
    na[pair] = sqrtf(ss);
    npn[pair] = sqrtf(ss_other);
  }

  bool isAnc = lane < 32;
  float sc = isAnc ? LOG2E : 1.0f;           // pre-scale anc so G arrives in log2 units
  __hip_bfloat16 b0 = __float2bfloat16(v.x * sc);
  __hip_bfloat16 b1 = __float2bfloat16(v.y * sc);
  __hip_bfloat16 b2 = __float2bfloat16(v.z * sc);
  __hip_bfloat16 b3 = __float2bfloat16(v.w * sc);
  ushort4 u;
  u.x = *(ushort*)&b0; u.y = *(ushort*)&b1;
  u.z = *(ushort*)&b2; u.w = *(ushort*)&b3;
  ushort* dst = isAnc ? (anc_bf + (size_t)pair * DIM + 4 * lane)
                      : (pos_bf + (size_t)pair * DIM + 4 * (lane - 32));
  *(ushort4*)dst = u;
}

// ---------------- main: fused GEMM (bf16 MFMA) + fixed-shift sum-exp ----------------
// grid = 64 rowblocks * 32 colsplits = 2048 blocks. Block: 4 waves x 32 rows,
// cols [cs*256, cs*256+256). A frags in regs (8 x short8); 2-deep B prefetch.
#define LSE_COMPUTE(BREG)                                                          \
  do {                                                                             \
    _Pragma("unroll")                                                              \
    for (int rt = 0; rt < 2; ++rt) {                                               \
      f32x4 acc = __builtin_amdgcn_mfma_f32_16x16x32_bf16(afrag[rt][0], BREG[0],   \
                                                          cinit, 0, 0, 0);         \
      acc = __builtin_amdgcn_mfma_f32_16x16x32_bf16(afrag[rt][1], BREG[1], acc, 0, 0, 0); \
      acc = __builtin_amdgcn_mfma_f32_16x16x32_bf16(afrag[rt][2], BREG[2], acc, 0, 0, 0); \
      acc = __builtin_amdgcn_mfma_f32_16x16x32_bf16(afrag[rt][3], BREG[3], acc, 0, 0, 0); \
      s[rt * 4 + 0] += fast_exp2(acc[0]);                                          \
      s[rt * 4 + 1] += fast_exp2(acc[1]);                                          \
      s[rt * 4 + 2] += fast_exp2(acc[2]);                                          \
      s[rt * 4 + 3] += fast_exp2(acc[3]);                                          \
    }                                                                              \
  } while (0)

__global__ __launch_bounds__(256, 4) void lse_kernel(
    const ushort* __restrict__ anc_bf, const ushort* __restrict__ pos_bf,
    float* __restrict__ part_s) {
  int tid = threadIdx.x;
  int w = tid >> 6, lane = tid & 63;
  int rb = blockIdx.x >> 5, cs = blockIdx.x & 31;
  int row0 = rb * ROWS_PER_BLOCK + w * 32;
  int colbase = cs * COLS_PER_BLOCK;
  int lrow = lane & 15, g = lane >> 4;

  // A fragments: 32 rows x 128 K in registers (8 x short8 = 32 VGPR)
  short8 afrag[2][4];
  #pragma unroll
  for (int rt = 0; rt < 2; ++rt) {
    const ushort* ab = anc_bf + (size_t)(row0 + rt * 16 + lrow) * DIM + g * 8;
    #pragma unroll
    for (int ks = 0; ks < 4; ++ks)
      afrag[rt][ks] = *(const short8*)(ab + ks * 32);
  }

  float s[8];
  #pragma unroll
  for (int i = 0; i < 8; ++i) s[i] = 0.f;
  const f32x4 cinit = {-SHIFT, -SHIFT, -SHIFT, -SHIFT};

  const ushort* bbase = pos_bf + (size_t)(colbase + lrow) * DIM + g * 8;
  short8 b0[4], b1[4];
  #pragma unroll
  for (int ks = 0; ks < 4; ++ks)
    b0[ks] = *(const short8*)(bbase + ks * 32);

  #pragma unroll 1
  for (int ct = 0; ct < CT; ct += 2) {
    const ushort* bp1 = bbase + (size_t)(ct + 1) * 16 * DIM;
    #pragma unroll
    for (int ks = 0; ks < 4; ++ks)
      b1[ks] = *(const short8*)(bp1 + ks * 32);
    LSE_COMPUTE(b0);
    int ctn = (ct + 2 < CT) ? ct + 2 : 0;   // clamp: dummy reload on last iter
    const ushort* bp2 = bbase + (size_t)ctn * 16 * DIM;
    #pragma unroll
    for (int ks = 0; ks < 4; ++ks)
      b0[ks] = *(const short8*)(bp2 + ks * 32);
    LSE_COMPUTE(b1);
  }

  // reduce s across the 16 lanes sharing each row (xor within lrow)
  #pragma unroll
  for (int i = 0; i < 8; ++i) {
    float ss = s[i];
    ss += __shfl_xor(ss, 1);
    ss += __shfl_xor(ss, 2);
    ss += __shfl_xor(ss, 4);
    ss += __shfl_xor(ss, 8);
    s[i] = ss;
  }
  if (lrow == 0) {
    #pragma unroll
    for (int rt = 0; rt < 2; ++rt)
      #pragma unroll
      for (int r = 0; r < 4; ++r)
        part_s[(size_t)cs * N_PAIR + (row0 + rt * 16 + g * 4 + r)] = s[rt * 4 + r];
  }
}

// ---------------- merge: combine column splits, add diag/norm terms ----------------
__global__ __launch_bounds__(256) void merge_kernel(
    const float* __restrict__ part_s,
    const float* __restrict__ diag, const float* __restrict__ na,
    const float* __restrict__ npn, float* __restrict__ blocksum) {
  int i = blockIdx.x * 256 + threadIdx.x;
  float S = 0.f;
  #pragma unroll
  for (int c = 0; c < CS; ++c)
    S += part_s[(size_t)c * N_PAIR + i];
  float lse = (SHIFT + log2f(S)) * LN2;
  float contrib = (lse - diag[i]) * (1.0f / N_PAIR)
                + L2REG * (na[i] * (1.0f / N_PAIR) + npn[i] * (1.0f / DIM));
  #pragma unroll
  for (int off = 32; off; off >>= 1) contrib += __shfl_xor(contrib, off);
  __shared__ float red[4];
  int lane = threadIdx.x & 63, wv = threadIdx.x >> 6;
  if (lane == 0) red[wv] = contrib;
  __syncthreads();
  if (threadIdx.x == 0)
    blocksum[blockIdx.x] = red[0] + red[1] + red[2] + red[3];
}

// ---------------- final: reduce 32 block sums ----------------
__global__ __launch_bounds__(64) void final_kernel(
    const float* __restrict__ blocksum, float* __restrict__ out, int nblocks) {
  float v = ((int)threadIdx.x < nblocks) ? blocksum[threadIdx.x] : 0.f;
  #pragma unroll
  for (int off = 32; off; off >>= 1) v += __shfl_xor(v, off);
  if (threadIdx.x == 0) out[0] = v;
}

extern "C" void kernel_launch(void* const* d_in, const int* in_sizes, int n_in,
                              void* d_out, int out_size, void* d_ws, size_t ws_size,
                              hipStream_t stream) {
  const float* img = (const float*)d_in[0];
  float* out = (float*)d_out;

  char* w = (char*)d_ws;
  ushort* anc_bf = (ushort*)w;                                  // 2 MB
  ushort* pos_bf = (ushort*)(w + (size_t)2 * 1024 * 1024);      // 2 MB
  float* diag = (float*)(w + (size_t)4 * 1024 * 1024);          // 32 KB
  float* na = diag + N_PAIR;                                    // 32 KB
  float* npn = na + N_PAIR;                                     // 32 KB
  float* part_s = npn + N_PAIR;                                 // 1 MB  [cs][row]
  float* blocksum = part_s + (size_t)N_PAIR * CS;               // 128 B

  prep_kernel<<<N_PAIR / 4, 256, 0, stream>>>(img, anc_bf, pos_bf, diag, na, npn);
  lse_kernel<<<(N_PAIR / ROWS_PER_BLOCK) * CS, 256, 0, stream>>>(anc_bf, pos_bf, part_s);
  merge_kernel<<<N_PAIR / 256, 256, 0, stream>>>(part_s, diag, na, npn, blocksum);
  final_kernel<<<1, 64, 0, stream>>>(blocksum, out, N_PAIR / 256);
}

// Round 4
// 42.903 us; speedup vs baseline: 1.9233x; 1.9233x over previous
//
#include <hip/hip_runtime.h>
#include <hip/hip_bf16.h>
#include <math.h>

#define N_PAIR 8192
#define DIM 128
#define L2REG 0.05f
#define LOG2E 1.44269504088896340736f
#define LN2 0.69314718055994530942f
#define SHIFT 64.0f

#define CS 32                           // column splits
#define BM 256                          // rows per block (4 waves x 64 rows)
#define COLS_PER_BLOCK (N_PAIR / CS)    // 256
#define STAGE_COLS 32                   // cols staged per LDS buffer
#define NSTAGES (COLS_PER_BLOCK / STAGE_COLS)  // 8

typedef __attribute__((ext_vector_type(8))) short short8;
typedef __attribute__((ext_vector_type(4))) float f32x4;

static __device__ __forceinline__ float fast_exp2(float x) {
#if __has_builtin(__builtin_amdgcn_exp2f)
  return __builtin_amdgcn_exp2f(x);
#else
  float r;
  asm("v_exp_f32 %0, %1" : "=v"(r) : "v"(x));
  return r;
#endif
}

static __device__ __forceinline__ void gload_lds16(const void* g, void* l) {
  __builtin_amdgcn_global_load_lds(
      (const __attribute__((address_space(1))) unsigned int*)g,
      (__attribute__((address_space(3))) unsigned int*)l, 16, 0, 0);
}

// ---------------- prep: deinterleave, scale anc by log2e, cast bf16, norms + diag ----
// one wave per pair (pair = 256 contiguous floats); 4 pairs per block.
// lanes 0-31: anc (row 2i), lanes 32-63: pos (row 2i+1); 1 float4 per lane.
__global__ __launch_bounds__(256) void prep_kernel(
    const float* __restrict__ img,
    ushort* __restrict__ anc_bf, ushort* __restrict__ pos_bf,
    float* __restrict__ diag, float* __restrict__ na, float* __restrict__ npn) {
  int pair = blockIdx.x * 4 + (threadIdx.x >> 6);
  int lane = threadIdx.x & 63;
  const float4* base = (const float4*)(img + (size_t)pair * 2 * DIM);
  float4 v = base[lane];
  float4 o;
  o.x = __shfl_xor(v.x, 32);
  o.y = __shfl_xor(v.y, 32);
  o.z = __shfl_xor(v.z, 32);
  o.w = __shfl_xor(v.w, 32);

  float ss = v.x * v.x + v.y * v.y + v.z * v.z + v.w * v.w;
  float sd = v.x * o.x + v.y * o.y + v.z * o.z + v.w * o.w;
  #pragma unroll
  for (int off = 1; off < 32; off <<= 1) {   // reduce within each 32-lane half
    ss += __shfl_xor(ss, off);
    sd += __shfl_xor(sd, off);
  }
  float ss_other = __shfl_xor(ss, 32);
  if (lane == 0) {
    diag[pair] = sd;
    na[pair] = sqrtf(ss);
    npn[pair] = sqrtf(ss_other);
  }

  bool isAnc = lane < 32;
  float sc = isAnc ? LOG2E : 1.0f;           // pre-scale anc: G arrives in log2 units
  __hip_bfloat16 b0 = __float2bfloat16(v.x * sc);
  __hip_bfloat16 b1 = __float2bfloat16(v.y * sc);
  __hip_bfloat16 b2 = __float2bfloat16(v.z * sc);
  __hip_bfloat16 b3 = __float2bfloat16(v.w * sc);
  ushort4 u;
  u.x = *(ushort*)&b0; u.y = *(ushort*)&b1;
  u.z = *(ushort*)&b2; u.w = *(ushort*)&b3;
  ushort* dst = isAnc ? (anc_bf + (size_t)pair * DIM + 4 * lane)
                      : (pos_bf + (size_t)pair * DIM + 4 * (lane - 32));
  *(ushort4*)dst = u;
}

// ---------------- main: LDS-staged B + reg-resident A + fixed-shift sum-exp --------
// grid = 32 rowblocks * 32 colsplits = 1024 blocks (exactly 4/CU).
// Block: 4 waves x 64 rows = 256 rows, cols [cs*256, cs*256+256).
// B staged 32 cols (8KB) at a time via global_load_lds, double-buffered,
// XOR-swizzled (chunk16 ^= col&7) with linear LDS dest + pre-swizzled global src.
__global__ __launch_bounds__(256, 4) void lse_kernel(
    const ushort* __restrict__ anc_bf, const ushort* __restrict__ pos_bf,
    float* __restrict__ part_s) {
  __shared__ short8 ldsb[2][512];   // 2 x 8KB

  int tid = threadIdx.x;
  int w = tid >> 6, lane = tid & 63;
  int rb = blockIdx.x >> 5, cs = blockIdx.x & 31;
  int row0 = rb * BM + w * 64;
  int colbase = cs * COLS_PER_BLOCK;
  int lrow = lane & 15, g = lane >> 4;

  // A fragments: 64 rows x 128 K resident in registers (16 x short8 = 64 VGPR)
  short8 afrag[4][4];
  #pragma unroll
  for (int rt = 0; rt < 4; ++rt) {
    const ushort* ab = anc_bf + (size_t)(row0 + rt * 16 + lrow) * DIM + g * 8;
    #pragma unroll
    for (int ks = 0; ks < 4; ++ks)
      afrag[rt][ks] = *(const short8*)(ab + ks * 64 / 2 * 2);  // + ks*32 elems
  }

  float s[16];
  #pragma unroll
  for (int i = 0; i < 16; ++i) s[i] = 0.f;
  const f32x4 cinit = {-SHIFT, -SHIFT, -SHIFT, -SHIFT};

  // per-wave stage: 2 x 1KB chunks (j = 2w, 2w+1); lane l writes LDS16[j*64+l],
  // fetching global chunk (j*64+l) ^ (((j*4 + (l>>4)) & 7))   [16B units]
  const char* pbase = (const char*)(pos_bf + (size_t)colbase * DIM);
  int j0 = w * 2;
  int srcoff0 = j0 * 1024 + ((lane * 16) ^ ((((j0 << 2) + (lane >> 4)) & 7) << 4));
  int j1 = j0 + 1;
  int srcoff1 = j1 * 1024 + ((lane * 16) ^ ((((j1 << 2) + (lane >> 4)) & 7) << 4));

#define STAGE(ST, BUF)                                                         \
  do {                                                                         \
    const char* pb_ = pbase + (size_t)(ST) * STAGE_COLS * DIM * 2;             \
    gload_lds16(pb_ + srcoff0, &ldsb[BUF][j0 * 64]);                           \
    gload_lds16(pb_ + srcoff1, &ldsb[BUF][j1 * 64]);                           \
  } while (0)

#define TILE_COMPUTE(BUF, T)                                                   \
  do {                                                                         \
    short8 b[4];                                                               \
    _Pragma("unroll")                                                          \
    for (int ks = 0; ks < 4; ++ks) {                                           \
      int idx = ((((T) * 16 + lrow) << 4) + (ks << 2) + g) ^ (lrow & 7);       \
      b[ks] = ldsb[BUF][idx];                                                  \
    }                                                                          \
    _Pragma("unroll")                                                          \
    for (int rt = 0; rt < 4; ++rt) {                                           \
      f32x4 acc = __builtin_amdgcn_mfma_f32_16x16x32_bf16(afrag[rt][0], b[0],  \
                                                          cinit, 0, 0, 0);     \
      acc = __builtin_amdgcn_mfma_f32_16x16x32_bf16(afrag[rt][1], b[1], acc, 0, 0, 0); \
      acc = __builtin_amdgcn_mfma_f32_16x16x32_bf16(afrag[rt][2], b[2], acc, 0, 0, 0); \
      acc = __builtin_amdgcn_mfma_f32_16x16x32_bf16(afrag[rt][3], b[3], acc, 0, 0, 0); \
      s[rt * 4 + 0] += fast_exp2(acc[0]);                                      \
      s[rt * 4 + 1] += fast_exp2(acc[1]);                                      \
      s[rt * 4 + 2] += fast_exp2(acc[2]);                                      \
      s[rt * 4 + 3] += fast_exp2(acc[3]);                                      \
    }                                                                          \
  } while (0)

  STAGE(0, 0);
  __syncthreads();
  #pragma unroll 1
  for (int st = 0; st < NSTAGES; ++st) {
    int buf = st & 1;
    if (st + 1 < NSTAGES) STAGE(st + 1, buf ^ 1);
    TILE_COMPUTE(buf, 0);
    TILE_COMPUTE(buf, 1);
    __syncthreads();
  }

  // reduce s across the 16 lanes sharing each row
  #pragma unroll
  for (int i = 0; i < 16; ++i) {
    float ss = s[i];
    ss += __shfl_xor(ss, 1);
    ss += __shfl_xor(ss, 2);
    ss += __shfl_xor(ss, 4);
    ss += __shfl_xor(ss, 8);
    s[i] = ss;
  }
  if (lrow == 0) {
    #pragma unroll
    for (int rt = 0; rt < 4; ++rt)
      #pragma unroll
      for (int r = 0; r < 4; ++r)
        part_s[(size_t)cs * N_PAIR + (row0 + rt * 16 + g * 4 + r)] = s[rt * 4 + r];
  }
#undef STAGE
#undef TILE_COMPUTE
}

// ---------------- merge: combine column splits, add diag/norm terms ----------------
__global__ __launch_bounds__(256) void merge_kernel(
    const float* __restrict__ part_s,
    const float* __restrict__ diag, const float* __restrict__ na,
    const float* __restrict__ npn, float* __restrict__ blocksum) {
  int i = blockIdx.x * 256 + threadIdx.x;
  float S = 0.f;
  #pragma unroll
  for (int c = 0; c < CS; ++c)
    S += part_s[(size_t)c * N_PAIR + i];
  float lse = (SHIFT + log2f(S)) * LN2;
  float contrib = (lse - diag[i]) * (1.0f / N_PAIR)
                + L2REG * (na[i] * (1.0f / N_PAIR) + npn[i] * (1.0f / DIM));
  #pragma unroll
  for (int off = 32; off; off >>= 1) contrib += __shfl_xor(contrib, off);
  __shared__ float red[4];
  int lane = threadIdx.x & 63, wv = threadIdx.x >> 6;
  if (lane == 0) red[wv] = contrib;
  __syncthreads();
  if (threadIdx.x == 0)
    blocksum[blockIdx.x] = red[0] + red[1] + red[2] + red[3];
}

// ---------------- final: reduce 32 block sums ----------------
__global__ __launch_bounds__(64) void final_kernel(
    const float* __restrict__ blocksum, float* __restrict__ out, int nblocks) {
  float v = ((int)threadIdx.x < nblocks) ? blocksum[threadIdx.x] : 0.f;
  #pragma unroll
  for (int off = 32; off; off >>= 1) v += __shfl_xor(v, off);
  if (threadIdx.x == 0) out[0] = v;
}

extern "C" void kernel_launch(void* const* d_in, const int* in_sizes, int n_in,
                              void* d_out, int out_size, void* d_ws, size_t ws_size,
                              hipStream_t stream) {
  const float* img = (const float*)d_in[0];
  float* out = (float*)d_out;

  char* w = (char*)d_ws;
  ushort* anc_bf = (ushort*)w;                                  // 2 MB
  ushort* pos_bf = (ushort*)(w + (size_t)2 * 1024 * 1024);      // 2 MB
  float* diag = (float*)(w + (size_t)4 * 1024 * 1024);          // 32 KB
  float* na = diag + N_PAIR;                                    // 32 KB
  float* npn = na + N_PAIR;                                     // 32 KB
  float* part_s = npn + N_PAIR;                                 // 1 MB  [cs][row]
  float* blocksum = part_s + (size_t)N_PAIR * CS;               // 128 B

  prep_kernel<<<N_PAIR / 4, 256, 0, stream>>>(img, anc_bf, pos_bf, diag, na, npn);
  lse_kernel<<<(N_PAIR / BM) * CS, 256, 0, stream>>>(anc_bf, pos_bf, part_s);
  merge_kernel<<<N_PAIR / 256, 256, 0, stream>>>(part_s, diag, na, npn, blocksum);
  final_kernel<<<1, 64, 0, stream>>>(blocksum, out, N_PAIR / 256);
}

// Round 5
// 36.433 us; speedup vs baseline: 2.2648x; 1.1776x over previous
//
#include <hip/hip_runtime.h>
#include <hip/hip_bf16.h>
#include <math.h>

#define N_PAIR 8192
#define DIM 128
#define L2REG 0.05f
#define LOG2E 1.44269504088896340736f
#define LN2 0.69314718055994530942f
#define SHIFT 64.0f

#define CS 32                           // column splits
#define BM 256                          // rows per block (4 waves x 64 rows)
#define COLS_PER_BLOCK (N_PAIR / CS)    // 256
#define NTILES (COLS_PER_BLOCK / 16)    // 16

typedef __attribute__((ext_vector_type(8))) short short8;
typedef __attribute__((ext_vector_type(4))) float f32x4;

static __device__ __forceinline__ float fast_exp2(float x) {
#if __has_builtin(__builtin_amdgcn_exp2f)
  return __builtin_amdgcn_exp2f(x);
#else
  float r;
  asm("v_exp_f32 %0, %1" : "=v"(r) : "v"(x));
  return r;
#endif
}

static __device__ __forceinline__ void gload_lds16(const void* g, void* l) {
  __builtin_amdgcn_global_load_lds(
      (const __attribute__((address_space(1))) unsigned int*)g,
      (__attribute__((address_space(3))) unsigned int*)l, 16, 0, 0);
}

// ---------------- prep: deinterleave, scale anc by log2e, cast bf16, norms + diag ----
// one wave per pair (pair = 256 contiguous floats); 4 pairs per block.
// lanes 0-31: anc (row 2i), lanes 32-63: pos (row 2i+1); 1 float4 per lane.
__global__ __launch_bounds__(256) void prep_kernel(
    const float* __restrict__ img,
    ushort* __restrict__ anc_bf, ushort* __restrict__ pos_bf,
    float* __restrict__ diag, float* __restrict__ na, float* __restrict__ npn) {
  int pair = blockIdx.x * 4 + (threadIdx.x >> 6);
  int lane = threadIdx.x & 63;
  const float4* base = (const float4*)(img + (size_t)pair * 2 * DIM);
  float4 v = base[lane];
  float4 o;
  o.x = __shfl_xor(v.x, 32);
  o.y = __shfl_xor(v.y, 32);
  o.z = __shfl_xor(v.z, 32);
  o.w = __shfl_xor(v.w, 32);

  float ss = v.x * v.x + v.y * v.y + v.z * v.z + v.w * v.w;
  float sd = v.x * o.x + v.y * o.y + v.z * o.z + v.w * o.w;
  #pragma unroll
  for (int off = 1; off < 32; off <<= 1) {   // reduce within each 32-lane half
    ss += __shfl_xor(ss, off);
    sd += __shfl_xor(sd, off);
  }
  float ss_other = __shfl_xor(ss, 32);
  if (lane == 0) {
    diag[pair] = sd;
    na[pair] = sqrtf(ss);
    npn[pair] = sqrtf(ss_other);
  }

  bool isAnc = lane < 32;
  float sc = isAnc ? LOG2E : 1.0f;           // pre-scale anc: G arrives in log2 units
  __hip_bfloat16 b0 = __float2bfloat16(v.x * sc);
  __hip_bfloat16 b1 = __float2bfloat16(v.y * sc);
  __hip_bfloat16 b2 = __float2bfloat16(v.z * sc);
  __hip_bfloat16 b3 = __float2bfloat16(v.w * sc);
  ushort4 u;
  u.x = *(ushort*)&b0; u.y = *(ushort*)&b1;
  u.z = *(ushort*)&b2; u.w = *(ushort*)&b3;
  ushort* dst = isAnc ? (anc_bf + (size_t)pair * DIM + 4 * lane)
                      : (pos_bf + (size_t)pair * DIM + 4 * (lane - 32));
  *(ushort4*)dst = u;
}

// ---------------- main: full-panel LDS (one barrier) + reg A + fixed-shift sum-exp --
// grid = 32 rowblocks * 32 colsplits = 1024 blocks, 2 blocks/CU (LDS-limited).
// Block: 4 waves x 64 rows = 256 rows, cols [cs*256, cs*256+256).
// Whole 64KB B panel staged once via global_load_lds (linear dest, swizzled src),
// then a barrier-free fully-unrolled MFMA + exp2 region.
__global__ __launch_bounds__(256, 2) void lse_kernel(
    const ushort* __restrict__ anc_bf, const ushort* __restrict__ pos_bf,
    float* __restrict__ part_s) {
  __shared__ short8 ldsb[4096];   // 64 KB: slot i = col*16 + (ks*4+g), swizzled

  int tid = threadIdx.x;
  int w = tid >> 6, lane = tid & 63;
  int rb = blockIdx.x >> 5, cs = blockIdx.x & 31;
  int row0 = rb * BM + w * 64;
  int colbase = cs * COLS_PER_BLOCK;
  int lrow = lane & 15, g = lane >> 4;

  // stage whole B panel: LDS slot i gets global 16B-chunk i ^ ((i>>4)&7)
  // (dest is wave-uniform base + lane*16: i = t*256 + w*64 + lane)
  const char* pbase = (const char*)(pos_bf + (size_t)colbase * DIM);
  #pragma unroll
  for (int t = 0; t < 16; ++t) {
    int i = t * 256 + tid;
    int src = (i ^ ((i >> 4) & 7)) << 4;
    gload_lds16(pbase + src, &ldsb[i]);
  }

  // A fragments: 64 rows x 128 K resident in registers (16 x short8 = 64 VGPR)
  short8 afrag[4][4];
  #pragma unroll
  for (int rt = 0; rt < 4; ++rt) {
    const ushort* ab = anc_bf + (size_t)(row0 + rt * 16 + lrow) * DIM + g * 8;
    #pragma unroll
    for (int ks = 0; ks < 4; ++ks)
      afrag[rt][ks] = *(const short8*)(ab + ks * 32);
  }

  float s[16];
  #pragma unroll
  for (int i = 0; i < 16; ++i) s[i] = 0.f;
  const f32x4 cinit = {-SHIFT, -SHIFT, -SHIFT, -SHIFT};

  __syncthreads();   // the only barrier

  #pragma unroll
  for (int T = 0; T < NTILES; ++T) {
    short8 b[4];
    int col = (T << 4) + lrow;
    #pragma unroll
    for (int ks = 0; ks < 4; ++ks) {
      int idx = ((col << 4) + (ks << 2) + g) ^ (col & 7);
      b[ks] = ldsb[idx];
    }
    #pragma unroll
    for (int rt = 0; rt < 4; ++rt) {
      f32x4 acc = __builtin_amdgcn_mfma_f32_16x16x32_bf16(afrag[rt][0], b[0], cinit, 0, 0, 0);
      acc = __builtin_amdgcn_mfma_f32_16x16x32_bf16(afrag[rt][1], b[1], acc, 0, 0, 0);
      acc = __builtin_amdgcn_mfma_f32_16x16x32_bf16(afrag[rt][2], b[2], acc, 0, 0, 0);
      acc = __builtin_amdgcn_mfma_f32_16x16x32_bf16(afrag[rt][3], b[3], acc, 0, 0, 0);
      s[rt * 4 + 0] += fast_exp2(acc[0]);
      s[rt * 4 + 1] += fast_exp2(acc[1]);
      s[rt * 4 + 2] += fast_exp2(acc[2]);
      s[rt * 4 + 3] += fast_exp2(acc[3]);
    }
  }

  // reduce s across the 16 lanes sharing each row
  #pragma unroll
  for (int i = 0; i < 16; ++i) {
    float ss = s[i];
    ss += __shfl_xor(ss, 1);
    ss += __shfl_xor(ss, 2);
    ss += __shfl_xor(ss, 4);
    ss += __shfl_xor(ss, 8);
    s[i] = ss;
  }
  if (lrow == 0) {
    #pragma unroll
    for (int rt = 0; rt < 4; ++rt)
      #pragma unroll
      for (int r = 0; r < 4; ++r)
        part_s[(size_t)cs * N_PAIR + (row0 + rt * 16 + g * 4 + r)] = s[rt * 4 + r];
  }
}

// ---------------- merge: combine column splits, add diag/norm terms ----------------
__global__ __launch_bounds__(256) void merge_kernel(
    const float* __restrict__ part_s,
    const float* __restrict__ diag, const float* __restrict__ na,
    const float* __restrict__ npn, float* __restrict__ blocksum) {
  int i = blockIdx.x * 256 + threadIdx.x;
  float S = 0.f;
  #pragma unroll
  for (int c = 0; c < CS; ++c)
    S += part_s[(size_t)c * N_PAIR + i];
  float lse = (SHIFT + log2f(S)) * LN2;
  float contrib = (lse - diag[i]) * (1.0f / N_PAIR)
                + L2REG * (na[i] * (1.0f / N_PAIR) + npn[i] * (1.0f / DIM));
  #pragma unroll
  for (int off = 32; off; off >>= 1) contrib += __shfl_xor(contrib, off);
  __shared__ float red[4];
  int lane = threadIdx.x & 63, wv = threadIdx.x >> 6;
  if (lane == 0) red[wv] = contrib;
  __syncthreads();
  if (threadIdx.x == 0)
    blocksum[blockIdx.x] = red[0] + red[1] + red[2] + red[3];
}

// ---------------- final: reduce 32 block sums ----------------
__global__ __launch_bounds__(64) void final_kernel(
    const float* __restrict__ blocksum, float* __restrict__ out, int nblocks) {
  float v = ((int)threadIdx.x < nblocks) ? blocksum[threadIdx.x] : 0.f;
  #pragma unroll
  for (int off = 32; off; off >>= 1) v += __shfl_xor(v, off);
  if (threadIdx.x == 0) out[0] = v;
}

extern "C" void kernel_launch(void* const* d_in, const int* in_sizes, int n_in,
                              void* d_out, int out_size, void* d_ws, size_t ws_size,
                              hipStream_t stream) {
  const float* img = (const float*)d_in[0];
  float* out = (float*)d_out;

  char* w = (char*)d_ws;
  ushort* anc_bf = (ushort*)w;                                  // 2 MB
  ushort* pos_bf = (ushort*)(w + (size_t)2 * 1024 * 1024);      // 2 MB
  float* diag = (float*)(w + (size_t)4 * 1024 * 1024);          // 32 KB
  float* na = diag + N_PAIR;                                    // 32 KB
  float* npn = na + N_PAIR;                                     // 32 KB
  float* part_s = npn + N_PAIR;                                 // 1 MB  [cs][row]
  float* blocksum = part_s + (size_t)N_PAIR * CS;               // 128 B

  prep_kernel<<<N_PAIR / 4, 256, 0, stream>>>(img, anc_bf, pos_bf, diag, na, npn);
  lse_kernel<<<(N_PAIR / BM) * CS, 256, 0, stream>>>(anc_bf, pos_bf, part_s);
  merge_kernel<<<N_PAIR / 256, 256, 0, stream>>>(part_s, diag, na, npn, blocksum);
  final_kernel<<<1, 64, 0, stream>>>(blocksum, out, N_PAIR / 256);
}

// Round 6
// 36.299 us; speedup vs baseline: 2.2732x; 1.0037x over previous
//
#include <hip/hip_runtime.h>
#include <hip/hip_bf16.h>
#include <math.h>

#define N_PAIR 8192
#define DIM 128
#define L2REG 0.05f
#define LOG2E 1.44269504088896340736f
#define LN2 0.69314718055994530942f
#define SHIFT 64.0f

#define CS 32                           // column splits
#define BM 256                          // rows per block (4 waves x 64 rows)
#define COLS_PER_BLOCK (N_PAIR / CS)    // 256
#define NTILES (COLS_PER_BLOCK / 16)    // 16

typedef __attribute__((ext_vector_type(8))) short short8;
typedef __attribute__((ext_vector_type(4))) float f32x4;

static __device__ __forceinline__ float fast_exp2(float x) {
#if __has_builtin(__builtin_amdgcn_exp2f)
  return __builtin_amdgcn_exp2f(x);
#else
  float r;
  asm("v_exp_f32 %0, %1" : "=v"(r) : "v"(x));
  return r;
#endif
}

static __device__ __forceinline__ void gload_lds16(const void* g, void* l) {
  __builtin_amdgcn_global_load_lds(
      (const __attribute__((address_space(1))) unsigned int*)g,
      (__attribute__((address_space(3))) unsigned int*)l, 16, 0, 0);
}

// ---------------- prep: deinterleave, scale anc by log2e, cast bf16, norms + diag ----
// one wave per pair (pair = 256 contiguous floats); 4 pairs per block.
// lanes 0-31: anc (row 2i), lanes 32-63: pos (row 2i+1); 1 float4 per lane.
__global__ __launch_bounds__(256) void prep_kernel(
    const float* __restrict__ img,
    ushort* __restrict__ anc_bf, ushort* __restrict__ pos_bf,
    float* __restrict__ diag, float* __restrict__ na, float* __restrict__ npn) {
  int pair = blockIdx.x * 4 + (threadIdx.x >> 6);
  int lane = threadIdx.x & 63;
  const float4* base = (const float4*)(img + (size_t)pair * 2 * DIM);
  float4 v = base[lane];
  float4 o;
  o.x = __shfl_xor(v.x, 32);
  o.y = __shfl_xor(v.y, 32);
  o.z = __shfl_xor(v.z, 32);
  o.w = __shfl_xor(v.w, 32);

  float ss = v.x * v.x + v.y * v.y + v.z * v.z + v.w * v.w;
  float sd = v.x * o.x + v.y * o.y + v.z * o.z + v.w * o.w;
  #pragma unroll
  for (int off = 1; off < 32; off <<= 1) {   // reduce within each 32-lane half
    ss += __shfl_xor(ss, off);
    sd += __shfl_xor(sd, off);
  }
  float ss_other = __shfl_xor(ss, 32);
  if (lane == 0) {
    diag[pair] = sd;
    na[pair] = sqrtf(ss);
    npn[pair] = sqrtf(ss_other);
  }

  bool isAnc = lane < 32;
  float sc = isAnc ? LOG2E : 1.0f;           // pre-scale anc: G arrives in log2 units
  __hip_bfloat16 b0 = __float2bfloat16(v.x * sc);
  __hip_bfloat16 b1 = __float2bfloat16(v.y * sc);
  __hip_bfloat16 b2 = __float2bfloat16(v.z * sc);
  __hip_bfloat16 b3 = __float2bfloat16(v.w * sc);
  ushort4 u;
  u.x = *(ushort*)&b0; u.y = *(ushort*)&b1;
  u.z = *(ushort*)&b2; u.w = *(ushort*)&b3;
  ushort* dst = isAnc ? (anc_bf + (size_t)pair * DIM + 4 * lane)
                      : (pos_bf + (size_t)pair * DIM + 4 * (lane - 32));
  *(ushort4*)dst = u;
}

// ---------------- main: full-panel LDS (one barrier) + reg A + fixed-shift sum-exp --
// grid = 1024 blocks (2/CU, LDS-limited). Block: 4 waves x 64 rows = 256 rows,
// cols [cs*256, +256). XCD-grouped remap: assuming xcd = blockIdx%8 round-robin,
// each XCD owns an 8rb x 16cs region of the tile grid, so panels are fetched from
// L3 once per XCD and then served from that XCD's L2 (12 MB L3 traffic vs 128 MB).
__global__ __launch_bounds__(256, 2) void lse_kernel(
    const ushort* __restrict__ anc_bf, const ushort* __restrict__ pos_bf,
    float* __restrict__ part_s) {
  __shared__ short8 ldsb[4096];   // 64 KB: slot i = col*16 + (ks*4+g), swizzled

  int tid = threadIdx.x;
  int w = tid >> 6, lane = tid & 63;

  // XCD-grouped bijective remap of the 32x32 (rb, cs) grid
  int n = blockIdx.x;
  int xcd = n & 7, m = n >> 3;                 // m in [0,128)
  int rb = (xcd & 3) * 8 + (m & 7);            // 8 row-blocks per region
  int cs = (xcd >> 2) * 16 + (m >> 3);         // 16 col-splits per region

  int row0 = rb * BM + w * 64;
  int colbase = cs * COLS_PER_BLOCK;
  int lrow = lane & 15, g = lane >> 4;

  // stage whole B panel: LDS slot i gets global 16B-chunk i ^ ((i>>4)&7)
  // (dest is wave-uniform base + lane*16: i = t*256 + w*64 + lane)
  const char* pbase = (const char*)(pos_bf + (size_t)colbase * DIM);
  #pragma unroll
  for (int t = 0; t < 16; ++t) {
    int i = t * 256 + tid;
    int src = (i ^ ((i >> 4) & 7)) << 4;
    gload_lds16(pbase + src, &ldsb[i]);
  }

  // A fragments: 64 rows x 128 K resident in registers (16 x short8 = 64 VGPR)
  short8 afrag[4][4];
  #pragma unroll
  for (int rt = 0; rt < 4; ++rt) {
    const ushort* ab = anc_bf + (size_t)(row0 + rt * 16 + lrow) * DIM + g * 8;
    #pragma unroll
    for (int ks = 0; ks < 4; ++ks)
      afrag[rt][ks] = *(const short8*)(ab + ks * 32);
  }

  float s[16];
  #pragma unroll
  for (int i = 0; i < 16; ++i) s[i] = 0.f;
  const f32x4 cinit = {-SHIFT, -SHIFT, -SHIFT, -SHIFT};

  __syncthreads();   // the only barrier

  #pragma unroll
  for (int T = 0; T < NTILES; ++T) {
    short8 b[4];
    int col = (T << 4) + lrow;
    #pragma unroll
    for (int ks = 0; ks < 4; ++ks) {
      int idx = ((col << 4) + (ks << 2) + g) ^ (col & 7);
      b[ks] = ldsb[idx];
    }
    #pragma unroll
    for (int rt = 0; rt < 4; ++rt) {
      f32x4 acc = __builtin_amdgcn_mfma_f32_16x16x32_bf16(afrag[rt][0], b[0], cinit, 0, 0, 0);
      acc = __builtin_amdgcn_mfma_f32_16x16x32_bf16(afrag[rt][1], b[1], acc, 0, 0, 0);
      acc = __builtin_amdgcn_mfma_f32_16x16x32_bf16(afrag[rt][2], b[2], acc, 0, 0, 0);
      acc = __builtin_amdgcn_mfma_f32_16x16x32_bf16(afrag[rt][3], b[3], acc, 0, 0, 0);
      s[rt * 4 + 0] += fast_exp2(acc[0]);
      s[rt * 4 + 1] += fast_exp2(acc[1]);
      s[rt * 4 + 2] += fast_exp2(acc[2]);
      s[rt * 4 + 3] += fast_exp2(acc[3]);
    }
  }

  // reduce s across the 16 lanes sharing each row
  #pragma unroll
  for (int i = 0; i < 16; ++i) {
    float ss = s[i];
    ss += __shfl_xor(ss, 1);
    ss += __shfl_xor(ss, 2);
    ss += __shfl_xor(ss, 4);
    ss += __shfl_xor(ss, 8);
    s[i] = ss;
  }
  if (lrow == 0) {
    #pragma unroll
    for (int rt = 0; rt < 4; ++rt)
      #pragma unroll
      for (int r = 0; r < 4; ++r)
        part_s[(size_t)cs * N_PAIR + (row0 + rt * 16 + g * 4 + r)] = s[rt * 4 + r];
  }
}

// ---------------- merge: combine column splits, add diag/norm terms ----------------
__global__ __launch_bounds__(256) void merge_kernel(
    const float* __restrict__ part_s,
    const float* __restrict__ diag, const float* __restrict__ na,
    const float* __restrict__ npn, float* __restrict__ blocksum) {
  int i = blockIdx.x * 256 + threadIdx.x;
  float S = 0.f;
  #pragma unroll
  for (int c = 0; c < CS; ++c)
    S += part_s[(size_t)c * N_PAIR + i];
  float lse = (SHIFT + log2f(S)) * LN2;
  float contrib = (lse - diag[i]) * (1.0f / N_PAIR)
                + L2REG * (na[i] * (1.0f / N_PAIR) + npn[i] * (1.0f / DIM));
  #pragma unroll
  for (int off = 32; off; off >>= 1) contrib += __shfl_xor(contrib, off);
  __shared__ float red[4];
  int lane = threadIdx.x & 63, wv = threadIdx.x >> 6;
  if (lane == 0) red[wv] = contrib;
  __syncthreads();
  if (threadIdx.x == 0)
    blocksum[blockIdx.x] = red[0] + red[1] + red[2] + red[3];
}

// ---------------- final: reduce 32 block sums ----------------
__global__ __launch_bounds__(64) void final_kernel(
    const float* __restrict__ blocksum, float* __restrict__ out, int nblocks) {
  float v = ((int)threadIdx.x < nblocks) ? blocksum[threadIdx.x] : 0.f;
  #pragma unroll
  for (int off = 32; off; off >>= 1) v += __shfl_xor(v, off);
  if (threadIdx.x == 0) out[0] = v;
}

extern "C" void kernel_launch(void* const* d_in, const int* in_sizes, int n_in,
                              void* d_out, int out_size, void* d_ws, size_t ws_size,
                              hipStream_t stream) {
  const float* img = (const float*)d_in[0];
  float* out = (float*)d_out;

  char* w = (char*)d_ws;
  ushort* anc_bf = (ushort*)w;                                  // 2 MB
  ushort* pos_bf = (ushort*)(w + (size_t)2 * 1024 * 1024);      // 2 MB
  float* diag = (float*)(w + (size_t)4 * 1024 * 1024);          // 32 KB
  float* na = diag + N_PAIR;                                    // 32 KB
  float* npn = na + N_PAIR;                                     // 32 KB
  float* part_s = npn + N_PAIR;                                 // 1 MB  [cs][row]
  float* blocksum = part_s + (size_t)N_PAIR * CS;               // 128 B

  prep_kernel<<<N_PAIR / 4, 256, 0, stream>>>(img, anc_bf, pos_bf, diag, na, npn);
  lse_kernel<<<(N_PAIR / BM) * CS, 256, 0, stream>>>(anc_bf, pos_bf, part_s);
  merge_kernel<<<N_PAIR / 256, 256, 0, stream>>>(part_s, diag, na, npn, blocksum);
  final_kernel<<<1, 64, 0, stream>>>(blocksum, out, N_PAIR / 256);
}